// Round 1
// baseline (169.281 us; speedup 1.0000x reference)
//
#include <hip/hip_runtime.h>
#include <math.h>

#define DIM 128
#define HID 256
#define NE  8
#define NTOK 131072

typedef __attribute__((ext_vector_type(8)))  short short8;
typedef __attribute__((ext_vector_type(16))) float f32x16;

static __device__ __forceinline__ unsigned short f2bf(float f) {
    unsigned int u = __float_as_uint(f);
    return (unsigned short)((u + 0x7FFFu + ((u >> 16) & 1u)) >> 16);
}

// ---------------------------------------------------------------------------
// Kernel 1: W1 [E][D][H] f32 -> bf16 fragment-linear layout in ws.
// Frag elem (e, hrt, kt, lane, j) = W1[e][kt*16 + (lane>>5)*8 + j][hrt*32 + (lane&31)]
// flat = ((((e*8)+hrt)*8+kt)*64+lane)*8 + j   (total 2^18 = 262144)
// ---------------------------------------------------------------------------
__global__ void prep_w1(const float* __restrict__ W1, unsigned short* __restrict__ wf) {
    int f = blockIdx.x * 256 + threadIdx.x;
    int j   = f & 7;
    int l   = (f >> 3) & 63;
    int kt  = (f >> 9) & 7;
    int hrt = (f >> 12) & 7;
    int e   = f >> 15;
    int k = kt * 16 + ((l >> 5) * 8) + j;
    int h = hrt * 32 + (l & 31);
    wf[f] = f2bf(W1[((size_t)e * DIM + k) * HID + h]);
}

// ---------------------------------------------------------------------------
// Kernel 2: gating softmax (exact fp32) + experts_used + per-block partials
// ---------------------------------------------------------------------------
__global__ void gates_kernel(const float* __restrict__ cp,
                             float* __restrict__ gates_out,
                             float* __restrict__ used_out,
                             float* __restrict__ part) {
    __shared__ float wp_[4][16];
    int tid = threadIdx.x;
    int b = blockIdx.x * 256 + tid;

    float g[8];
    {
        const float4* c4 = (const float4*)(cp + (size_t)b * NE);
        float4 a0 = c4[0], a1 = c4[1];
        g[0]=a0.x; g[1]=a0.y; g[2]=a0.z; g[3]=a0.w;
        g[4]=a1.x; g[5]=a1.y; g[6]=a1.z; g[7]=a1.w;
    }
    float m = g[0];
    #pragma unroll
    for (int i = 1; i < 8; ++i) m = fmaxf(m, g[i]);
    float s = 0.f;
    #pragma unroll
    for (int i = 0; i < 8; ++i) { g[i] = __expf(g[i] - m); s += g[i]; }
    float inv = 1.f / s;
    #pragma unroll
    for (int i = 0; i < 8; ++i) g[i] *= inv;

    {
        float4 o0 = make_float4(g[0], g[1], g[2], g[3]);
        float4 o1 = make_float4(g[4], g[5], g[6], g[7]);
        float4* g4 = (float4*)(gates_out + (size_t)b * NE);
        g4[0] = o0; g4[1] = o1;
    }
    float v[16];
    float used = 0.f;
    #pragma unroll
    for (int i = 0; i < 8; ++i) {
        float a = (g[i] > 0.01f) ? 1.f : 0.f;
        used += a;
        v[i] = g[i];
        v[8 + i] = a;
    }
    used_out[b] = used;

    // wave (64-lane) reduction then cross-wave via LDS (deterministic)
    #pragma unroll
    for (int d = 32; d >= 1; d >>= 1)
        #pragma unroll
        for (int i = 0; i < 16; ++i)
            v[i] += __shfl_down(v[i], d, 64);
    int lane = tid & 63, wid = tid >> 6;
    if (lane == 0)
        #pragma unroll
        for (int i = 0; i < 16; ++i) wp_[wid][i] = v[i];
    __syncthreads();
    if (tid < 16)
        part[(size_t)blockIdx.x * 16 + tid] =
            wp_[0][tid] + wp_[1][tid] + wp_[2][tid] + wp_[3][tid];
}

// ---------------------------------------------------------------------------
// Kernel 3: final reduce of 512 block-partials -> influence[8], act_count[8]
// ---------------------------------------------------------------------------
__global__ void reduce_kernel(const float* __restrict__ part,
                              float* __restrict__ inf_out,
                              float* __restrict__ cnt_out) {
    int t = threadIdx.x;
    if (t >= 16) return;
    float s = 0.f;
    for (int i = 0; i < 512; ++i) s += part[(size_t)i * 16 + t];
    if (t < 8) inf_out[t] = s;
    else       cnt_out[t - 8] = s;
}

// ---------------------------------------------------------------------------
// Kernel 4: main MoE. 512 thr = 8 waves (2 tokgrp x 4 hgrp), 256 tokens/block.
// A = W1 frags (rows = h) from ws (L2), B = x frags (cols = tokens) in regs.
// ---------------------------------------------------------------------------
__global__ __launch_bounds__(512, 2)
void moe_main(const float* __restrict__ x,
              const unsigned short* __restrict__ wf,
              const float* __restrict__ W2,
              const float* __restrict__ b1,
              const float* __restrict__ b2,
              const float* __restrict__ gates,
              float* __restrict__ pred_out) {
    __shared__ unsigned short xs[8 * 8 * 64 * 8];   // 64 KB frag-linear x tile
    __shared__ float w2s[NE * HID];                 // 8 KB
    __shared__ float b1s[NE * HID];                 // 8 KB
    __shared__ float gsh[256 * NE];                 // 8 KB
    __shared__ float ybuf[4][256];                  // 4 KB

    const int tid    = threadIdx.x;
    const int lane   = tid & 63;
    const int wid    = tid >> 6;
    const int hg     = wid & 3;    // h-group: 64 h each
    const int tokgrp = wid >> 2;   // token-group: 128 tokens each
    const int b0     = blockIdx.x * 256;

    // stage small tables (each is exactly 2048 floats = 512 float4)
    ((float4*)w2s)[tid] = ((const float4*)W2)[tid];
    ((float4*)b1s)[tid] = ((const float4*)b1)[tid];
    ((float4*)gsh)[tid] = ((const float4*)(gates + (size_t)b0 * NE))[tid];

    // stage x tile f32 -> bf16 frag layout
    {
        const float4* xg = (const float4*)(x + (size_t)b0 * DIM);
        #pragma unroll
        for (int it = 0; it < 16; ++it) {
            int f4 = tid + it * 512;          // 0..8191
            float4 v = xg[f4];
            int token = f4 >> 5;
            int kq = (f4 & 31) * 4;
            int tile = token >> 5;
            int l = (token & 31) + ((kq >> 3) & 1) * 32;
            int kt = kq >> 4;
            int j = kq & 7;                   // 0 or 4
            unsigned long long p =
                  (unsigned long long)f2bf(v.x)
                | ((unsigned long long)f2bf(v.y) << 16)
                | ((unsigned long long)f2bf(v.z) << 32)
                | ((unsigned long long)f2bf(v.w) << 48);
            *(unsigned long long*)&xs[(((tile * 8 + kt) * 64 + l) * 8) + j] = p;
        }
    }
    __syncthreads();

    // x fragments -> registers (reused across all 8 experts)
    short8 xf[4][8];
    #pragma unroll
    for (int tt = 0; tt < 4; ++tt)
        #pragma unroll
        for (int kt = 0; kt < 8; ++kt) {
            int tile = tokgrp * 4 + tt;
            xf[tt][kt] = *(const short8*)&xs[((tile * 8 + kt) * 64 + lane) * 8];
        }

    float pred = 0.f;  // valid for tid < 256 (token b0 + tid)
    const int g = lane >> 5;

    for (int e = 0; e < NE; ++e) {
        float ylane[4] = {0.f, 0.f, 0.f, 0.f};
        #pragma unroll
        for (int hr = 0; hr < 2; ++hr) {
            f32x16 acc[4];
            #pragma unroll
            for (int tt = 0; tt < 4; ++tt) acc[tt] = (f32x16)0.0f;
            const int hrt = hg * 2 + hr;
            const short8* wp = (const short8*)wf + ((size_t)(e * 8 + hrt) * 8) * 64 + lane;
            #pragma unroll
            for (int kt = 0; kt < 8; ++kt) {
                short8 wfr = wp[kt * 64];
                #pragma unroll
                for (int tt = 0; tt < 4; ++tt)
                    acc[tt] = __builtin_amdgcn_mfma_f32_32x32x16_bf16(
                        wfr, xf[tt][kt], acc[tt], 0, 0, 0);
            }
            // fold: y += relu(acc + b1) * W2 over this 32-h row tile
            #pragma unroll
            for (int tt = 0; tt < 4; ++tt) {
                float yp = 0.f;
                #pragma unroll
                for (int r = 0; r < 16; ++r) {
                    int row = (r & 3) + 8 * (r >> 2) + 4 * g;   // verified C/D map
                    int h = hg * 64 + hr * 32 + row;
                    float vv = acc[tt][r] + b1s[e * HID + h];
                    yp = fmaf(fmaxf(vv, 0.f), w2s[e * HID + h], yp);
                }
                ylane[tt] += yp;
            }
        }
        // reduce lane <-> lane+32 (same token col, complementary h rows)
        #pragma unroll
        for (int tt = 0; tt < 4; ++tt) {
            float y2 = ylane[tt] + __shfl_xor(ylane[tt], 32, 64);
            if (lane < 32)
                ybuf[hg][tokgrp * 128 + tt * 32 + lane] = y2;
        }
        __syncthreads();
        if (tid < 256) {
            float s = ybuf[0][tid] + ybuf[1][tid] + ybuf[2][tid] + ybuf[3][tid] + b2[e];
            float yv = 1.f / (1.f + __expf(-s));
            pred = fmaf(gsh[tid * NE + e], yv, pred);
        }
        __syncthreads();
    }
    if (tid < 256) pred_out[b0 + tid] = pred;
}

// ---------------------------------------------------------------------------
extern "C" void kernel_launch(void* const* d_in, const int* in_sizes, int n_in,
                              void* d_out, int out_size, void* d_ws, size_t ws_size,
                              hipStream_t stream) {
    (void)in_sizes; (void)n_in; (void)out_size; (void)ws_size;
    const float* x  = (const float*)d_in[0];
    const float* cp = (const float*)d_in[1];
    const float* W1 = (const float*)d_in[2];
    const float* b1 = (const float*)d_in[3];
    const float* W2 = (const float*)d_in[4];
    const float* b2 = (const float*)d_in[5];

    float* out   = (float*)d_out;
    float* pred  = out;                       // [131072]
    float* gates = out + 131072;              // [131072*8]
    float* used  = out + 1179648;             // [131072]
    float* inf   = out + 1310720;             // [8]
    float* cnt   = out + 1310728;             // [8]

    unsigned short* wf = (unsigned short*)d_ws;              // 512 KB frag W1
    float* part = (float*)((char*)d_ws + 512 * 1024);        // 32 KB partials

    prep_w1<<<dim3(1024), dim3(256), 0, stream>>>(W1, wf);
    gates_kernel<<<dim3(512), dim3(256), 0, stream>>>(cp, gates, used, part);
    reduce_kernel<<<dim3(1), dim3(64), 0, stream>>>(part, inf, cnt);
    moe_main<<<dim3(512), dim3(512), 0, stream>>>(x, wf, W2, b1, b2, gates, pred);
}

// Round 2
// 110.596 us; speedup vs baseline: 1.5306x; 1.5306x over previous
//
#include <hip/hip_runtime.h>
#include <math.h>

#define NE  8
#define HID 256

typedef __attribute__((ext_vector_type(8)))  short short8;
typedef __attribute__((ext_vector_type(16))) float f32x16;

static __device__ __forceinline__ unsigned short f2bf(float f) {
    unsigned int u = __float_as_uint(f);
    return (unsigned short)((u + 0x7FFFu + ((u >> 16) & 1u)) >> 16);
}

static __device__ __forceinline__ short8 pack8(float4 a, float4 b) {
    short8 r;
    r[0] = (short)f2bf(a.x); r[1] = (short)f2bf(a.y);
    r[2] = (short)f2bf(a.z); r[3] = (short)f2bf(a.w);
    r[4] = (short)f2bf(b.x); r[5] = (short)f2bf(b.y);
    r[6] = (short)f2bf(b.z); r[7] = (short)f2bf(b.w);
    return r;
}

// ---------------------------------------------------------------------------
// Kernel 1: W1 [E][128][256] + b1 [E][256] -> bf16 frag-linear, K padded to 144.
// frag elem (e, hrt<8, kt<9, lane, j) = W1aug[e][kt*16+(lane>>5)*8+j][hrt*32+(lane&31)]
// where W1aug[k=128] = b1 row, k>128 = 0.  73728 B per expert, contiguous.
// ---------------------------------------------------------------------------
__global__ void prep_w1(const float* __restrict__ W1, const float* __restrict__ b1,
                        unsigned short* __restrict__ wf) {
    int f = blockIdx.x * 256 + threadIdx.x;     // 294912 total
    int j  = f & 7;
    int l  = (f >> 3) & 63;
    int t  = f >> 9;                            // frag idx: e*72 + hrt*9 + kt
    int kt = t % 9;
    int t2 = t / 9;
    int hrt = t2 & 7;
    int e   = t2 >> 3;
    int k = kt * 16 + ((l >> 5) * 8) + j;
    int h = hrt * 32 + (l & 31);
    float v;
    if (k < 128)      v = W1[((size_t)e * 128 + k) * HID + h];
    else if (k == 128) v = b1[e * HID + h];
    else               v = 0.f;
    wf[f] = f2bf(v);
}

// ---------------------------------------------------------------------------
// Kernel 2: gating softmax (exact fp32) + experts_used + per-block partials
// ---------------------------------------------------------------------------
__global__ void gates_kernel(const float* __restrict__ cp,
                             float* __restrict__ gates_out,
                             float* __restrict__ used_out,
                             float* __restrict__ part) {
    __shared__ float wp_[4][16];
    int tid = threadIdx.x;
    int b = blockIdx.x * 256 + tid;

    float g[8];
    {
        const float4* c4 = (const float4*)(cp + (size_t)b * NE);
        float4 a0 = c4[0], a1 = c4[1];
        g[0]=a0.x; g[1]=a0.y; g[2]=a0.z; g[3]=a0.w;
        g[4]=a1.x; g[5]=a1.y; g[6]=a1.z; g[7]=a1.w;
    }
    float m = g[0];
    #pragma unroll
    for (int i = 1; i < 8; ++i) m = fmaxf(m, g[i]);
    float s = 0.f;
    #pragma unroll
    for (int i = 0; i < 8; ++i) { g[i] = __expf(g[i] - m); s += g[i]; }
    float inv = 1.f / s;
    #pragma unroll
    for (int i = 0; i < 8; ++i) g[i] *= inv;

    {
        float4 o0 = make_float4(g[0], g[1], g[2], g[3]);
        float4 o1 = make_float4(g[4], g[5], g[6], g[7]);
        float4* g4 = (float4*)(gates_out + (size_t)b * NE);
        g4[0] = o0; g4[1] = o1;
    }
    float v[16];
    float used = 0.f;
    #pragma unroll
    for (int i = 0; i < 8; ++i) {
        float a = (g[i] > 0.01f) ? 1.f : 0.f;
        used += a;
        v[i] = g[i];
        v[8 + i] = a;
    }
    used_out[b] = used;

    #pragma unroll
    for (int d = 32; d >= 1; d >>= 1)
        #pragma unroll
        for (int i = 0; i < 16; ++i)
            v[i] += __shfl_down(v[i], d, 64);
    int lane = tid & 63, wid = tid >> 6;
    if (lane == 0)
        #pragma unroll
        for (int i = 0; i < 16; ++i) wp_[wid][i] = v[i];
    __syncthreads();
    if (tid < 16)
        part[(size_t)blockIdx.x * 16 + tid] =
            wp_[0][tid] + wp_[1][tid] + wp_[2][tid] + wp_[3][tid];
}

__global__ void reduce_kernel(const float* __restrict__ part,
                              float* __restrict__ inf_out,
                              float* __restrict__ cnt_out) {
    int t = threadIdx.x;
    if (t >= 16) return;
    float s = 0.f;
    for (int i = 0; i < 512; ++i) s += part[(size_t)i * 16 + t];
    if (t < 8) inf_out[t] = s;
    else       cnt_out[t - 8] = s;
}

// ---------------------------------------------------------------------------
// Kernel 4: main MoE. 256 thr = 4 waves; each wave: 128 tokens x 256 h x 8 e.
// x frags pinned in 128 VGPRs; W1 double-buffered in LDS (2x72KB) via
// global_load_lds; b1 folded into MFMA via K=144 pad. No cross-wave combine.
// ---------------------------------------------------------------------------
__global__ __launch_bounds__(256, 1)
void moe_main(const float* __restrict__ x,
              const unsigned short* __restrict__ wf,
              const float* __restrict__ W2,
              const float* __restrict__ b2,
              const float* __restrict__ gates,
              float* __restrict__ pred_out) {
    __shared__ unsigned short W1s[2][8 * 9 * 64 * 8];   // 2 x 73728 B = 144 KB

    const int tid  = threadIdx.x;
    const int lane = tid & 63;
    const int wid  = tid >> 6;          // 0..3
    const int g    = lane >> 5;
    const int col  = lane & 31;
    const int tw   = blockIdx.x * 512 + wid * 128;   // wave token base

    // ---- issue stage of expert 0 into buf 0 (72 KB, 18 x 1KB per wave)
    {
        const char* src = (const char*)wf + (size_t)wid * 18 * 1024 + lane * 16;
        char* dst = (char*)&W1s[0][0] + wid * 18 * 1024;
        #pragma unroll
        for (int i = 0; i < 18; ++i)
            __builtin_amdgcn_global_load_lds(
                (const __attribute__((address_space(1))) unsigned int*)(src + i * 1024),
                (__attribute__((address_space(3))) unsigned int*)(dst + i * 1024),
                16, 0, 0);
    }

    // ---- x fragments -> registers (bf16), frag (tt,kt): token=tw+tt*32+col,
    //      k = kt*16 + g*8 + j  (matches verified round-1 mapping)
    short8 xf[4][8];
    #pragma unroll
    for (int tt = 0; tt < 4; ++tt) {
        const float* xr = x + ((size_t)(tw + tt * 32 + col)) * 128 + g * 8;
        #pragma unroll
        for (int kt = 0; kt < 8; ++kt) {
            float4 a = *(const float4*)(xr + kt * 16);
            float4 b = *(const float4*)(xr + kt * 16 + 4);
            xf[tt][kt] = pack8(a, b);
        }
    }
    // bias column frag: k=128 -> 1.0, k>128 -> 0
    short8 xfb = (short8)0;
    if (g == 0) xfb[0] = (short)0x3F80;

    float pred[4] = {0.f, 0.f, 0.f, 0.f};
    int p = 0;
    __syncthreads();   // drains vmcnt: stage(e0) + x loads complete

    for (int e = 0; e < NE; ++e) {
        if (e < 7) {
            const char* src = (const char*)wf + (size_t)(e + 1) * 73728
                            + (size_t)wid * 18 * 1024 + lane * 16;
            char* dst = (char*)&W1s[p ^ 1][0] + wid * 18 * 1024;
            #pragma unroll
            for (int i = 0; i < 18; ++i)
                __builtin_amdgcn_global_load_lds(
                    (const __attribute__((address_space(1))) unsigned int*)(src + i * 1024),
                    (__attribute__((address_space(3))) unsigned int*)(dst + i * 1024),
                    16, 0, 0);
        }

        float yacc[4] = {0.f, 0.f, 0.f, 0.f};
        for (int hrt = 0; hrt < 8; ++hrt) {
            short8 w1r[9];
            #pragma unroll
            for (int kt = 0; kt < 9; ++kt)
                w1r[kt] = *(const short8*)&W1s[p][((hrt * 9 + kt) * 64 + lane) * 8];

            f32x16 acc[4];
            #pragma unroll
            for (int tt = 0; tt < 4; ++tt) acc[tt] = (f32x16)0.0f;

            #pragma unroll
            for (int kt = 0; kt < 9; ++kt) {
                #pragma unroll
                for (int tt = 0; tt < 4; ++tt)
                    acc[tt] = __builtin_amdgcn_mfma_f32_32x32x16_bf16(
                        w1r[kt], (kt < 8) ? xf[tt][kt] : xfb, acc[tt], 0, 0, 0);
            }

            // fold: yacc += relu(acc) * w2   (h = hrt*32 + 8q + 4g + i)
            #pragma unroll
            for (int q = 0; q < 4; ++q) {
                float4 w2q = *(const float4*)&W2[(size_t)e * HID + hrt * 32 + q * 8 + g * 4];
                #pragma unroll
                for (int tt = 0; tt < 4; ++tt) {
                    yacc[tt] = fmaf(fmaxf(acc[tt][q * 4 + 0], 0.f), w2q.x, yacc[tt]);
                    yacc[tt] = fmaf(fmaxf(acc[tt][q * 4 + 1], 0.f), w2q.y, yacc[tt]);
                    yacc[tt] = fmaf(fmaxf(acc[tt][q * 4 + 2], 0.f), w2q.z, yacc[tt]);
                    yacc[tt] = fmaf(fmaxf(acc[tt][q * 4 + 3], 0.f), w2q.w, yacc[tt]);
                }
            }
        }

        // combine halves, sigmoid, gate-weight
        float bb = b2[e];
        #pragma unroll
        for (int tt = 0; tt < 4; ++tt) {
            float s = yacc[tt] + __shfl_xor(yacc[tt], 32, 64) + bb;
            float yv = 1.f / (1.f + __expf(-s));
            float gt = gates[(size_t)(tw + tt * 32 + col) * NE + e];
            pred[tt] = fmaf(gt, yv, pred[tt]);
        }

        __syncthreads();   // staging of buf p^1 done; all reads of buf p done
        p ^= 1;
    }

    #pragma unroll
    for (int tt = 0; tt < 4; ++tt)
        if (lane < 32) pred_out[tw + tt * 32 + col] = pred[tt];
}

// ---------------------------------------------------------------------------
extern "C" void kernel_launch(void* const* d_in, const int* in_sizes, int n_in,
                              void* d_out, int out_size, void* d_ws, size_t ws_size,
                              hipStream_t stream) {
    (void)in_sizes; (void)n_in; (void)out_size; (void)ws_size;
    const float* x  = (const float*)d_in[0];
    const float* cp = (const float*)d_in[1];
    const float* W1 = (const float*)d_in[2];
    const float* b1 = (const float*)d_in[3];
    const float* W2 = (const float*)d_in[4];
    const float* b2 = (const float*)d_in[5];

    float* out   = (float*)d_out;
    float* pred  = out;                       // [131072]
    float* gates = out + 131072;              // [131072*8]
    float* used  = out + 1179648;             // [131072]
    float* inf   = out + 1310720;             // [8]
    float* cnt   = out + 1310728;             // [8]

    unsigned short* wfrag = (unsigned short*)d_ws;           // 576 KB frag W1
    float* part = (float*)((char*)d_ws + 589824);            // 32 KB partials

    prep_w1<<<dim3(1152), dim3(256), 0, stream>>>(W1, b1, wfrag);
    gates_kernel<<<dim3(512), dim3(256), 0, stream>>>(cp, gates, used, part);
    reduce_kernel<<<dim3(1), dim3(64), 0, stream>>>(part, inf, cnt);
    moe_main<<<dim3(256), dim3(256), 0, stream>>>(x, wfrag, W2, b2, gates, pred);
}

// Round 3
// 97.480 us; speedup vs baseline: 1.7366x; 1.1345x over previous
//
#include <hip/hip_runtime.h>
#include <math.h>

#define NE  8
#define HID 256

typedef __attribute__((ext_vector_type(8)))  short short8;
typedef __attribute__((ext_vector_type(16))) float f32x16;

static __device__ __forceinline__ unsigned short f2bf(float f) {
    unsigned int u = __float_as_uint(f);
    return (unsigned short)((u + 0x7FFFu + ((u >> 16) & 1u)) >> 16);
}

static __device__ __forceinline__ short8 pack8(float4 a, float4 b) {
    short8 r;
    r[0] = (short)f2bf(a.x); r[1] = (short)f2bf(a.y);
    r[2] = (short)f2bf(a.z); r[3] = (short)f2bf(a.w);
    r[4] = (short)f2bf(b.x); r[5] = (short)f2bf(b.y);
    r[6] = (short)f2bf(b.z); r[7] = (short)f2bf(b.w);
    return r;
}

// ---------------------------------------------------------------------------
// Kernel 1 (blocks 0..1023): W1 [E][128][256] -> bf16 frag-linear (no K pad).
//   frag (e, hrt<8, kt<8): [lane][j] = W1[e][kt*16+(lane>>5)*8+j][hrt*32+(lane&31)]
//   1 KB per frag, 64 KB per expert, 512 KB total.
// Block 1024: pk table [e][hrt][q][g][8] f32: j<4 -> b1[h], j>=4 -> W2[h],
//   h = hrt*32 + q*8 + g*4 + (j&3).  16 KB.
// ---------------------------------------------------------------------------
__global__ void prep_w1(const float* __restrict__ W1, const float* __restrict__ b1,
                        const float* __restrict__ W2,
                        unsigned short* __restrict__ wfr, float* __restrict__ pk) {
    if (blockIdx.x < 1024) {
        int f = blockIdx.x * 256 + threadIdx.x;     // 262144 total
        int j   = f & 7;
        int l   = (f >> 3) & 63;
        int kt  = (f >> 9) & 7;
        int hrt = (f >> 12) & 7;
        int e   = f >> 15;
        int k = kt * 16 + ((l >> 5) * 8) + j;
        int h = hrt * 32 + (l & 31);
        wfr[f] = f2bf(W1[((size_t)e * 128 + k) * HID + h]);
    } else {
        for (int i = threadIdx.x; i < 4096; i += 256) {
            int j   = i & 7;
            int g   = (i >> 3) & 1;
            int q   = (i >> 4) & 3;
            int hrt = (i >> 6) & 7;
            int e   = i >> 9;
            int h = hrt * 32 + q * 8 + g * 4 + (j & 3);
            pk[i] = (j < 4) ? b1[e * HID + h] : W2[e * HID + h];
        }
    }
}

// ---------------------------------------------------------------------------
// Kernel 2: gating softmax (exact fp32) + experts_used + per-block partials
// ---------------------------------------------------------------------------
__global__ void gates_kernel(const float* __restrict__ cp,
                             float* __restrict__ gates_out,
                             float* __restrict__ used_out,
                             float* __restrict__ part) {
    __shared__ float wp_[4][16];
    int tid = threadIdx.x;
    int b = blockIdx.x * 256 + tid;

    float g[8];
    {
        const float4* c4 = (const float4*)(cp + (size_t)b * NE);
        float4 a0 = c4[0], a1 = c4[1];
        g[0]=a0.x; g[1]=a0.y; g[2]=a0.z; g[3]=a0.w;
        g[4]=a1.x; g[5]=a1.y; g[6]=a1.z; g[7]=a1.w;
    }
    float m = g[0];
    #pragma unroll
    for (int i = 1; i < 8; ++i) m = fmaxf(m, g[i]);
    float s = 0.f;
    #pragma unroll
    for (int i = 0; i < 8; ++i) { g[i] = __expf(g[i] - m); s += g[i]; }
    float inv = 1.f / s;
    #pragma unroll
    for (int i = 0; i < 8; ++i) g[i] *= inv;

    {
        float4 o0 = make_float4(g[0], g[1], g[2], g[3]);
        float4 o1 = make_float4(g[4], g[5], g[6], g[7]);
        float4* g4 = (float4*)(gates_out + (size_t)b * NE);
        g4[0] = o0; g4[1] = o1;
    }
    float v[16];
    float used = 0.f;
    #pragma unroll
    for (int i = 0; i < 8; ++i) {
        float a = (g[i] > 0.01f) ? 1.f : 0.f;
        used += a;
        v[i] = g[i];
        v[8 + i] = a;
    }
    used_out[b] = used;

    #pragma unroll
    for (int d = 32; d >= 1; d >>= 1)
        #pragma unroll
        for (int i = 0; i < 16; ++i)
            v[i] += __shfl_down(v[i], d, 64);
    int lane = tid & 63, wid = tid >> 6;
    if (lane == 0)
        #pragma unroll
        for (int i = 0; i < 16; ++i) wp_[wid][i] = v[i];
    __syncthreads();
    if (tid < 16)
        part[(size_t)blockIdx.x * 16 + tid] =
            wp_[0][tid] + wp_[1][tid] + wp_[2][tid] + wp_[3][tid];
}

__global__ void reduce_kernel(const float* __restrict__ part,
                              float* __restrict__ inf_out,
                              float* __restrict__ cnt_out) {
    int t = threadIdx.x;
    if (t >= 16) return;
    float s = 0.f;
    for (int i = 0; i < 512; ++i) s += part[(size_t)i * 16 + t];
    if (t < 8) inf_out[t] = s;
    else       cnt_out[t - 8] = s;
}

// ---------------------------------------------------------------------------
// Kernel 4: main MoE. 512 thr = 8 waves (2/SIMD); each wave: 64 tokens,
// all 256 h, all 8 experts. x frags pinned in 64 VGPRs; W1 double-buffered
// in LDS (2x64KB) via global_load_lds; b1/w2 via 16 KB broadcast table.
// ---------------------------------------------------------------------------
__global__ __launch_bounds__(512, 2)
void moe_main(const float* __restrict__ x,
              const unsigned short* __restrict__ wfr,
              const float* __restrict__ pk,
              const float* __restrict__ b2,
              const float* __restrict__ gates,
              float* __restrict__ pred_out) {
    __shared__ unsigned short W1s[2][8 * 8 * 64 * 8];   // 2 x 64 KB
    __shared__ float pks[4096];                         // 16 KB

    const int tid  = threadIdx.x;
    const int lane = tid & 63;
    const int wid  = tid >> 6;          // 0..7
    const int g    = lane >> 5;
    const int col  = lane & 31;
    const int tw   = blockIdx.x * 512 + wid * 64;   // wave token base

    // ---- issue stage of expert 0 into buf 0 (64 KB = 8 waves x 8 x 1KB)
    {
        const char* src = (const char*)wfr + (size_t)wid * 8192 + lane * 16;
        char* dst = (char*)&W1s[0][0] + wid * 8192;
        #pragma unroll
        for (int i = 0; i < 8; ++i)
            __builtin_amdgcn_global_load_lds(
                (const __attribute__((address_space(1))) unsigned int*)(src + i * 1024),
                (__attribute__((address_space(3))) unsigned int*)(dst + i * 1024),
                16, 0, 0);
    }
    // ---- pk table -> LDS (1024 float4)
    ((float4*)pks)[tid]       = ((const float4*)pk)[tid];
    ((float4*)pks)[tid + 512] = ((const float4*)pk)[tid + 512];

    // ---- x fragments -> registers: frag (tt<2, kt<8): token=tw+tt*32+col,
    //      k = kt*16 + g*8 + j
    short8 xf[2][8];
    #pragma unroll
    for (int tt = 0; tt < 2; ++tt) {
        const float* xr = x + ((size_t)(tw + tt * 32 + col)) * 128 + g * 8;
        #pragma unroll
        for (int kt = 0; kt < 8; ++kt) {
            float4 a = *(const float4*)(xr + kt * 16);
            float4 b = *(const float4*)(xr + kt * 16 + 4);
            xf[tt][kt] = pack8(a, b);
        }
    }

    float pred[2] = {0.f, 0.f};
    int p = 0;
    __syncthreads();   // drains vmcnt/lgkmcnt: stage(e0), pk, x loads complete

    for (int e = 0; e < NE; ++e) {
        if (e < 7) {
            const char* src = (const char*)wfr + (size_t)(e + 1) * 65536
                            + (size_t)wid * 8192 + lane * 16;
            char* dst = (char*)&W1s[p ^ 1][0] + wid * 8192;
            #pragma unroll
            for (int i = 0; i < 8; ++i)
                __builtin_amdgcn_global_load_lds(
                    (const __attribute__((address_space(1))) unsigned int*)(src + i * 1024),
                    (__attribute__((address_space(3))) unsigned int*)(dst + i * 1024),
                    16, 0, 0);
        }

        float yacc[2] = {0.f, 0.f};
        #pragma unroll 2
        for (int hrt = 0; hrt < 8; ++hrt) {
            short8 w1r[8];
            #pragma unroll
            for (int kt = 0; kt < 8; ++kt)
                w1r[kt] = *(const short8*)&W1s[p][((hrt * 8 + kt) * 64 + lane) * 8];

            f32x16 acc[2];
            acc[0] = (f32x16)0.0f;
            acc[1] = (f32x16)0.0f;

            #pragma unroll
            for (int kt = 0; kt < 8; ++kt) {
                acc[0] = __builtin_amdgcn_mfma_f32_32x32x16_bf16(
                    w1r[kt], xf[0][kt], acc[0], 0, 0, 0);
                acc[1] = __builtin_amdgcn_mfma_f32_32x32x16_bf16(
                    w1r[kt], xf[1][kt], acc[1], 0, 0, 0);
            }

            // epilogue: yacc += relu(acc + b1) * w2, h = hrt*32 + 8q + 4g + i
            #pragma unroll
            for (int q = 0; q < 4; ++q) {
                int base = (((e * 8 + hrt) * 4 + q) * 2 + g) * 8;
                float4 b1q = *(const float4*)&pks[base];
                float4 w2q = *(const float4*)&pks[base + 4];
                #pragma unroll
                for (int tt = 0; tt < 2; ++tt) {
                    yacc[tt] = fmaf(fmaxf(acc[tt][q * 4 + 0] + b1q.x, 0.f), w2q.x, yacc[tt]);
                    yacc[tt] = fmaf(fmaxf(acc[tt][q * 4 + 1] + b1q.y, 0.f), w2q.y, yacc[tt]);
                    yacc[tt] = fmaf(fmaxf(acc[tt][q * 4 + 2] + b1q.z, 0.f), w2q.z, yacc[tt]);
                    yacc[tt] = fmaf(fmaxf(acc[tt][q * 4 + 3] + b1q.w, 0.f), w2q.w, yacc[tt]);
                }
            }
        }

        // combine halves, sigmoid, gate-weight
        float bb = b2[e];
        #pragma unroll
        for (int tt = 0; tt < 2; ++tt) {
            float s = yacc[tt] + __shfl_xor(yacc[tt], 32, 64) + bb;
            float yv = 1.f / (1.f + __expf(-s));
            float gt = gates[(size_t)(tw + tt * 32 + col) * NE + e];
            pred[tt] = fmaf(gt, yv, pred[tt]);
        }

        __syncthreads();   // staging of buf p^1 done; all reads of buf p done
        p ^= 1;
    }

    #pragma unroll
    for (int tt = 0; tt < 2; ++tt)
        if (lane < 32) pred_out[tw + tt * 32 + col] = pred[tt];
}

// ---------------------------------------------------------------------------
extern "C" void kernel_launch(void* const* d_in, const int* in_sizes, int n_in,
                              void* d_out, int out_size, void* d_ws, size_t ws_size,
                              hipStream_t stream) {
    (void)in_sizes; (void)n_in; (void)out_size; (void)ws_size;
    const float* x  = (const float*)d_in[0];
    const float* cp = (const float*)d_in[1];
    const float* W1 = (const float*)d_in[2];
    const float* b1 = (const float*)d_in[3];
    const float* W2 = (const float*)d_in[4];
    const float* b2 = (const float*)d_in[5];

    float* out   = (float*)d_out;
    float* pred  = out;                       // [131072]
    float* gates = out + 131072;              // [131072*8]
    float* used  = out + 1179648;             // [131072]
    float* inf   = out + 1310720;             // [8]
    float* cnt   = out + 1310728;             // [8]

    unsigned short* wfrag = (unsigned short*)d_ws;           // 512 KB frag W1
    float* pk   = (float*)((char*)d_ws + 524288);            // 16 KB b1/w2 table
    float* part = (float*)((char*)d_ws + 540672);            // 32 KB partials

    prep_w1<<<dim3(1025), dim3(256), 0, stream>>>(W1, b1, W2, wfrag, pk);
    gates_kernel<<<dim3(512), dim3(256), 0, stream>>>(cp, gates, used, part);
    reduce_kernel<<<dim3(1), dim3(64), 0, stream>>>(part, inf, cnt);
    moe_main<<<dim3(256), dim3(512), 0, stream>>>(x, wfrag, pk, b2, gates, pred);
}